// Round 6
// baseline (38.231 us; speedup 1.0000x reference)
//
#include <hip/hip_runtime.h>
#include <hip/hip_bf16.h>

// Problem constants
#define PM 8        // groups
#define PK 4096     // codebook entries per group
#define PD 128      // dim
#define PN 8
#define PH 64
#define PW 64

typedef __attribute__((ext_vector_type(8))) short bf16x8;
typedef __attribute__((ext_vector_type(4))) float f32x4;
typedef __attribute__((ext_vector_type(8))) short short8v;

__device__ inline unsigned short f2bf_rne(float f) {
    unsigned int u = __float_as_uint(f);
    unsigned int r = (u + 0x7FFFu + ((u >> 16) & 1u)) >> 16;
    return (unsigned short)r;
}
__device__ inline float bf2f(unsigned short s) {
    return __uint_as_float(((unsigned int)s) << 16);
}

__device__ inline bf16x8 loadcvt8(const float* __restrict__ p) {
    f32x4 x0 = *(const f32x4*)p;
    f32x4 x1 = *(const f32x4*)(p + 4);
    bf16x8 r;
#pragma unroll
    for (int j = 0; j < 4; ++j) {
        r[j]     = (short)f2bf_rne(x0[j]);
        r[j + 4] = (short)f2bf_rne(x1[j]);
    }
    return r;
}

// ---------------------------------------------------------------------------
// Kernel 1 v3 (unchanged from R5, ~4 us): table[m,k,c] via LDS-staged wq,
// swapped-operand MFMA, packed 8 B stores.
// ---------------------------------------------------------------------------
__global__ __launch_bounds__(256) void build_table(
        const float* __restrict__ codebook,
        const float* __restrict__ wq,
        const float* __restrict__ bq,
        unsigned short* __restrict__ table) {
    __shared__ unsigned short ldsA[2048 * 8];   // 2048 frag-units x 16 B = 32 KB
    __shared__ float lds_bq[PD];
    const int b = blockIdx.x;
    const int m = b & 7;
    const int kt0 = (b >> 3) * 128;
    const int tid = threadIdx.x;
    const int wv = tid >> 6;
    const int l  = tid & 63;
    const int lr = l & 15;
    const int lg = l >> 4;

    const float* cb = codebook + (size_t)m * PK * PD;
    const float* wm = wq + (size_t)m * PD * PD;

    if (tid < PD) lds_bq[tid] = bq[m * PD + tid];

    // Stage wq -> LDS frag-major: unit u = (cs<<4)|(kk<<2)|lg holds
    // wq[cs*16 + slot][kk*32 + lg*8 .. +8) as bf16x8 at slot index.
    {
        const int lr_s = tid & 15;
        const int u0 = (tid >> 4) * 8;
#pragma unroll
        for (int i = 0; i < 8; ++i) {
            const int u  = u0 + i;
            const int cs = u >> 4;
            const int kk = (u >> 2) & 3;
            const int lgs = u & 3;
            bf16x8 v = loadcvt8(wm + (size_t)(cs * 16 + lr_s) * PD + kk * 32 + lgs * 8);
            *(bf16x8*)&ldsA[(size_t)(u * 16 + lr_s) * 8] = v;
        }
    }

    // Codebook B-frags (per-wave k rows), loaded while staging is in flight.
    bf16x8 bfragc[2][4];
#pragma unroll
    for (int ks = 0; ks < 2; ++ks) {
        const int k = kt0 + wv * 32 + ks * 16 + lr;
        const float* src = cb + (size_t)k * PD + lg * 8;
#pragma unroll
        for (int kk = 0; kk < 4; ++kk) {
            bfragc[ks][kk] = loadcvt8(src + kk * 32);
        }
    }
    __syncthreads();

#pragma unroll
    for (int cs = 0; cs < 8; ++cs) {
        bf16x8 afragw[4];
#pragma unroll
        for (int kk = 0; kk < 4; ++kk) {
            const int u = (cs << 4) | (kk << 2) | lg;
            afragw[kk] = *(const bf16x8*)&ldsA[(size_t)(u * 16 + lr) * 8];
        }
        const f32x4 bias4 = *(const f32x4*)&lds_bq[cs * 16 + lg * 4];
#pragma unroll
        for (int ks = 0; ks < 2; ++ks) {
            f32x4 acc = {0.f, 0.f, 0.f, 0.f};
#pragma unroll
            for (int kk = 0; kk < 4; ++kk) {
                acc = __builtin_amdgcn_mfma_f32_16x16x32_bf16(
                        afragw[kk], bfragc[ks][kk], acc, 0, 0, 0);
            }
            // D[row = c = cs*16 + lg*4 + j][col = k = kt0+wv*32+ks*16+lr]
            const int k = kt0 + wv * 32 + ks * 16 + lr;
            unsigned int p0 = (unsigned int)f2bf_rne(acc[0] + bias4[0])
                            | ((unsigned int)f2bf_rne(acc[1] + bias4[1]) << 16);
            unsigned int p1 = (unsigned int)f2bf_rne(acc[2] + bias4[2])
                            | ((unsigned int)f2bf_rne(acc[3] + bias4[3]) << 16);
            uint2 pk; pk.x = p0; pk.y = p1;
            *(uint2*)&table[((size_t)(m * PK + k)) * PD + cs * 16 + lg * 4] = pk;
        }
    }
}

// ---------------------------------------------------------------------------
// Kernel 2 v5: cooperative row gather + LDS transpose.
// Phase 1: thread (p = tid>>2, sub = tid&3). The 4 sub-lanes of a position
//   share its code; gather instr i reads, per wave, 16 positions x one 64 B
//   line = 16 cacheline touches (vs 64 in the per-lane-random layout). Code
//   load: 4 lanes broadcast-share an address; wave spans 512 B = 8 lines
//   (vs 32). Convert bf16->f32, write LDS[w][c] stride 129 floats:
//   write banks (p + 8*sub + j)%32 = exact 2-way (free, m136);
//   read banks (w + c)%32 = conflict-free.
// Phase 2: lane = w; 32 scalar LDS reads + proven 256 B/instr coalesced
//   plain stores. Stores depend only on LDS, not on in-flight global loads.
// LDS 33 KB -> 4 blocks/CU (write streams saturate at low occupancy).
// ---------------------------------------------------------------------------
__global__ __launch_bounds__(256) void gather_scatter(
        const int* __restrict__ codes,
        const unsigned short* __restrict__ table,
        float* __restrict__ out) {
    __shared__ float ldsF[64 * 129];
    const int b = blockIdx.x;
    const int m = b & 7;
    const int rest = b >> 3;
    const int n = rest >> 6;
    const int h = rest & 63;
    const int tid = threadIdx.x;

    // ---- Phase 1: cooperative gather + transpose into LDS ----
    {
        const int p   = tid >> 2;   // position (w) 0..63
        const int sub = tid & 3;    // 16 B sub-chunk of each 64 B line
        const int code = codes[((n * PH + h) * PW + p) * PM + m];
        const unsigned short* row = table + ((size_t)m * PK + code) * PD;
        short8v v[4];
#pragma unroll
        for (int i = 0; i < 4; ++i) {
            v[i] = *(const short8v*)(row + i * 32 + sub * 8);
        }
        float* dst = &ldsF[p * 129 + sub * 8];
#pragma unroll
        for (int i = 0; i < 4; ++i) {
#pragma unroll
            for (int j = 0; j < 8; ++j) {
                dst[i * 32 + j] = bf2f((unsigned short)v[i][j]);
            }
        }
    }
    __syncthreads();

    // ---- Phase 2: transpose-read + coalesced plain stores ----
    const int w  = tid & 63;
    const int c0 = (tid >> 6) * 32;
    const float* src = &ldsF[w * 129 + c0];
    float* ob = out + (((size_t)n * (PM * PD) + m * PD + c0) * PH + h) * PW + w;
#pragma unroll
    for (int j = 0; j < 32; ++j) {
        ob[(size_t)j * (PH * PW)] = src[j];
    }
}

// ---------------------------------------------------------------------------
// Fallback (only if ws_size < table size): fused direct compute, fp32.
// ---------------------------------------------------------------------------
__global__ __launch_bounds__(256) void fused_direct(
        const int* __restrict__ codes,
        const float* __restrict__ codebook,
        const float* __restrict__ wq,
        const float* __restrict__ bq,
        float* __restrict__ out) {
    __shared__ float rows[PW][133];
    const int b = blockIdx.x;
    const int m = b & 7;
    const int rest = b >> 3;
    const int n = rest >> 6;
    const int h = rest & 63;
    const int tid = threadIdx.x;

    for (int idx = tid; idx < PW * 32; idx += 256) {
        const int r = idx >> 5;
        const int e = (idx & 31) * 4;
        const int code = codes[((n * PH + h) * PW + r) * PM + m];
        const float* src = codebook + ((size_t)m * PK + code) * PD + e;
#pragma unroll
        for (int j = 0; j < 4; ++j) rows[r][e + j] = src[j];
    }
    __syncthreads();

    const int w = tid & 63;
    const int cb0 = (tid >> 6) * 32;
    float* ob = out + (((size_t)n * (PM * PD) + m * PD + cb0) * PH + h) * PW + w;
    for (int ci = 0; ci < 32; ++ci) {
        const int c = cb0 + ci;
        const float* wr = wq + ((size_t)m * PD + c) * PD;
        float acc = bq[m * PD + c];
#pragma unroll 4
        for (int d = 0; d < PD; ++d) acc += rows[w][d] * wr[d];
        ob[(size_t)ci * (PH * PW)] = acc;
    }
}

extern "C" void kernel_launch(void* const* d_in, const int* in_sizes, int n_in,
                              void* d_out, int out_size, void* d_ws, size_t ws_size,
                              hipStream_t stream) {
    const int*   codes    = (const int*)  d_in[0];
    const float* codebook = (const float*)d_in[1];
    const float* wq       = (const float*)d_in[2];
    const float* bq       = (const float*)d_in[3];
    float* out = (float*)d_out;

    const size_t table_bytes = (size_t)PM * PK * PD * sizeof(unsigned short); // 8 MB
    if (ws_size >= table_bytes) {
        unsigned short* table = (unsigned short*)d_ws;
        build_table<<<dim3(256), dim3(256), 0, stream>>>(codebook, wq, bq, table);
        gather_scatter<<<dim3(PM * PN * PH), dim3(256), 0, stream>>>(codes, table, out);
    } else {
        fused_direct<<<dim3(PM * PN * PH), dim3(256), 0, stream>>>(codes, codebook, wq, bq, out);
    }
}